// Round 1
// baseline (284.852 us; speedup 1.0000x reference)
//
#include <hip/hip_runtime.h>
#include <hip/hip_bf16.h>
#include <math.h>

// Problem constants (fixed by reference)
#define N_NODES 4096
#define N_SUBS  1024
#define NFEAT   128
#define HIDDEN  512
#define NHEADS  8
#define DHEAD   64
#define CAP     512   // max neighbors per row (actual ~42 +/- 7, binomial; 512 is >60 sigma)

// ---------------------------------------------------------------------------
// Generic fp32 tiled GEMM: C[M,N] = A[M,K] @ B[K,N] (+bias). M,N %64==0, K%16==0.
// ---------------------------------------------------------------------------
#define BM 64
#define BN 64
#define BK 16
__global__ __launch_bounds__(256) void gemm_f32(const float* __restrict__ A,
                                                const float* __restrict__ B,
                                                const float* __restrict__ bias,
                                                float* __restrict__ C,
                                                int M, int N, int K) {
    __shared__ float As[BK][BM];
    __shared__ float Bs[BK][BN];
    const int tid = threadIdx.x;
    const int bm = blockIdx.y * BM;
    const int bn = blockIdx.x * BN;
    const int tr = tid >> 4;   // 0..15
    const int tc = tid & 15;   // 0..15
    float acc[4][4] = {};
    for (int k0 = 0; k0 < K; k0 += BK) {
#pragma unroll
        for (int i = 0; i < 4; i++) {
            int idx = tid + i * 256;     // 0..1023
            int m = idx / BK;
            int k = idx % BK;
            As[k][m] = A[(size_t)(bm + m) * K + k0 + k];
        }
#pragma unroll
        for (int i = 0; i < 4; i++) {
            int idx = tid + i * 256;
            int k = idx / BN;
            int n = idx % BN;
            Bs[k][n] = B[(size_t)(k0 + k) * N + bn + n];
        }
        __syncthreads();
#pragma unroll
        for (int k = 0; k < BK; k++) {
            const float4 a4 = reinterpret_cast<const float4*>(&As[k][0])[tr];
            const float4 b4 = reinterpret_cast<const float4*>(&Bs[k][0])[tc];
            float a[4] = {a4.x, a4.y, a4.z, a4.w};
            float b[4] = {b4.x, b4.y, b4.z, b4.w};
#pragma unroll
            for (int i = 0; i < 4; i++)
#pragma unroll
                for (int j = 0; j < 4; j++)
                    acc[i][j] += a[i] * b[j];
        }
        __syncthreads();
    }
#pragma unroll
    for (int i = 0; i < 4; i++) {
        int m = bm + tr * 4 + i;
#pragma unroll
        for (int j = 0; j < 4; j++) {
            int n = bn + tc * 4 + j;
            float v = acc[i][j];
            if (bias) v += bias[n];
            C[(size_t)m * N + n] = v;
        }
    }
}

// ---------------------------------------------------------------------------
// fs[h,n] = sum_d Wh[n, h*64+d]*asrc[h,d];  fd likewise with adst.
// One block per node, 512 threads (8 head-waves of 64 lanes).
// ---------------------------------------------------------------------------
__global__ __launch_bounds__(512) void fsfd_kernel(const float* __restrict__ Wh,
                                                   const float* __restrict__ asrc,
                                                   const float* __restrict__ adst,
                                                   float* __restrict__ fs,
                                                   float* __restrict__ fd, int N) {
    const int n = blockIdx.x;
    const int tid = threadIdx.x;
    const int h = tid >> 6;
    const int d = tid & 63;
    float w = Wh[(size_t)n * HIDDEN + tid];
    float vs = w * asrc[h * DHEAD + d];
    float vd = w * adst[h * DHEAD + d];
#pragma unroll
    for (int off = 32; off >= 1; off >>= 1) {
        vs += __shfl_xor(vs, off, 64);
        vd += __shfl_xor(vd, off, 64);
    }
    if (d == 0) {
        fs[h * N + n] = vs;
        fd[h * N + n] = vd;
    }
}

// ---------------------------------------------------------------------------
// One GAT attention layer row: out[i,h,d] = elu( sum_j alpha[h,i,j]*Wh[j,h,d] )
// alpha = softmax over neighbors j (adj[i,j]>0) of leaky_relu(fs[h,i]+fd[h,j]).
// Block = 512 threads = 8 head-waves; one block per row i.
// ---------------------------------------------------------------------------
__global__ __launch_bounds__(512) void gat_kernel(const float* __restrict__ adj,
                                                  const float* __restrict__ Wh,
                                                  const float* __restrict__ fs,
                                                  const float* __restrict__ fd,
                                                  float* __restrict__ out, int N) {
    __shared__ int nbr[CAP];
    __shared__ float ex[NHEADS][CAP];
    __shared__ int cnt;
    const int i = blockIdx.x;
    const int tid = threadIdx.x;
    if (tid == 0) cnt = 0;
    __syncthreads();
    const float* row = adj + (size_t)i * N;
    for (int j = tid; j < N; j += 512) {
        if (row[j] > 0.0f) {
            int p = atomicAdd(&cnt, 1);
            if (p < CAP) nbr[p] = j;
        }
    }
    __syncthreads();
    const int C = cnt < CAP ? cnt : CAP;
    const int h = tid >> 6;
    const int lane = tid & 63;
    const float fsi = fs[h * N + i];
    // pass 1: e = leaky_relu(fs_i + fd_j), wave max
    float m = -1e30f;
    for (int k = lane; k < C; k += 64) {
        float e = fsi + fd[h * N + nbr[k]];
        e = e > 0.0f ? e : 0.2f * e;
        ex[h][k] = e;
        m = fmaxf(m, e);
    }
#pragma unroll
    for (int off = 32; off >= 1; off >>= 1) m = fmaxf(m, __shfl_xor(m, off, 64));
    // pass 2: exp & sum
    float ssum = 0.0f;
    for (int k = lane; k < C; k += 64) {
        float v = __expf(ex[h][k] - m);
        ex[h][k] = v;
        ssum += v;
    }
#pragma unroll
    for (int off = 32; off >= 1; off >>= 1) ssum += __shfl_xor(ssum, off, 64);
    __syncthreads();  // ex[] visible across lanes
    const float inv = 1.0f / ssum;  // self-loop guarantees C>=1, ssum>0
    float acc = 0.0f;
    for (int k = 0; k < C; k++) {
        acc += ex[h][k] * Wh[(size_t)nbr[k] * HIDDEN + h * DHEAD + lane];
    }
    acc *= inv;
    out[(size_t)i * HIDDEN + h * DHEAD + lane] = acc > 0.0f ? acc : __expf(acc) - 1.0f;
}

// ---------------------------------------------------------------------------
// Segment-mean pooling. seg_ids sorted. One block per substation, 512 threads
// (one per hidden dim). Binary search for the segment range.
// ---------------------------------------------------------------------------
__global__ __launch_bounds__(512) void pool_kernel(const float* __restrict__ hin,
                                                   const int* __restrict__ seg,
                                                   float* __restrict__ sout) {
    const int s = blockIdx.x;
    const int d = threadIdx.x;
    int lo = 0, hi = N_NODES;
    while (lo < hi) { int mid = (lo + hi) >> 1; if (seg[mid] < s) lo = mid + 1; else hi = mid; }
    const int start = lo;
    hi = N_NODES;
    while (lo < hi) { int mid = (lo + hi) >> 1; if (seg[mid] < s + 1) lo = mid + 1; else hi = mid; }
    const int end = lo;
    float acc = 0.0f;
    for (int r = start; r < end; r++) acc += hin[(size_t)r * HIDDEN + d];
    const int c = end - start;
    sout[(size_t)s * HIDDEN + d] = acc / (c > 0 ? (float)c : 1.0f);
}

// ---------------------------------------------------------------------------
extern "C" void kernel_launch(void* const* d_in, const int* in_sizes, int n_in,
                              void* d_out, int out_size, void* d_ws, size_t ws_size,
                              hipStream_t stream) {
    const float* x        = (const float*)d_in[0];
    const float* adj_node = (const float*)d_in[1];
    const float* adj_sub  = (const float*)d_in[2];
    const int*   seg_ids  = (const int*)d_in[3];
    const float* lin_w    = (const float*)d_in[4];
    const float* lin_b    = (const float*)d_in[5];
    // _stacked_gats bug: every layer reads the ORIGINAL h; only the LAST
    // layer's output survives. Use layer index 1 only.
    const float* node_W1    = (const float*)d_in[6]  + HIDDEN * HIDDEN;
    const float* node_asrc1 = (const float*)d_in[7]  + NHEADS * DHEAD;
    const float* node_adst1 = (const float*)d_in[8]  + NHEADS * DHEAD;
    const float* sub_W1     = (const float*)d_in[9]  + HIDDEN * HIDDEN;
    const float* sub_asrc1  = (const float*)d_in[10] + NHEADS * DHEAD;
    const float* sub_adst1  = (const float*)d_in[11] + NHEADS * DHEAD;
    float* out = (float*)d_out;

    // Workspace layout (needs ~16.3 MB):
    //  bufA (8MB): h0, later reused as node-GAT output
    //  bufB (8MB): Wh_node; later reused: s_pooled(2MB) | Wh_sub(2MB) | fs_s | fd_s
    //  fs_n/fd_n at +16MB (128KB each)
    char* ws = (char*)d_ws;
    float* bufA  = (float*)(ws);                               // 4096*512 f32
    float* bufB  = (float*)(ws + (size_t)8 * 1024 * 1024);     // 4096*512 f32
    float* fs_n  = (float*)(ws + (size_t)16 * 1024 * 1024);
    float* fd_n  = (float*)(ws + (size_t)16 * 1024 * 1024 + 131072);
    float* h0    = bufA;
    float* wh_n  = bufB;
    float* gatom = bufA;                                        // node GAT out
    float* sp    = bufB;                                        // 1024*512 f32
    float* wh_s  = bufB + (size_t)N_SUBS * HIDDEN;              // 1024*512 f32
    float* fs_s  = bufB + (size_t)2 * N_SUBS * HIDDEN;
    float* fd_s  = fs_s + NHEADS * N_SUBS;

    // 1. h0 = x @ lin_w + lin_b   [4096,128]@[128,512]
    gemm_f32<<<dim3(HIDDEN / BN, N_NODES / BM), 256, 0, stream>>>(
        x, lin_w, lin_b, h0, N_NODES, HIDDEN, NFEAT);
    // 2. Wh_node = h0 @ node_W[1]  [4096,512]@[512,512]
    gemm_f32<<<dim3(HIDDEN / BN, N_NODES / BM), 256, 0, stream>>>(
        h0, node_W1, nullptr, wh_n, N_NODES, HIDDEN, HIDDEN);
    // 3. attention logits fs/fd
    fsfd_kernel<<<N_NODES, 512, 0, stream>>>(wh_n, node_asrc1, node_adst1,
                                             fs_n, fd_n, N_NODES);
    // 4. node GAT layer (writes over h0 buffer; h0 dead after step 2)
    gat_kernel<<<N_NODES, 512, 0, stream>>>(adj_node, wh_n, fs_n, fd_n,
                                            gatom, N_NODES);
    // 5. segment-mean pool (writes over Wh_node buffer; dead after step 4)
    pool_kernel<<<N_SUBS, 512, 0, stream>>>(gatom, seg_ids, sp);
    // 6. Wh_sub = s @ sub_W[1]  [1024,512]@[512,512]
    gemm_f32<<<dim3(HIDDEN / BN, N_SUBS / BM), 256, 0, stream>>>(
        sp, sub_W1, nullptr, wh_s, N_SUBS, HIDDEN, HIDDEN);
    // 7. sub attention logits
    fsfd_kernel<<<N_SUBS, 512, 0, stream>>>(wh_s, sub_asrc1, sub_adst1,
                                            fs_s, fd_s, N_SUBS);
    // 8. sub GAT layer -> final output
    gat_kernel<<<N_SUBS, 512, 0, stream>>>(adj_sub, wh_s, fs_s, fd_s,
                                           out, N_SUBS);
}